// Round 23
// baseline (3609.120 us; speedup 1.0000x reference)
//
#include <hip/hip_runtime.h>
#include <math.h>

// ---- problem constants ----
constexpr int B_  = 8;
constexpr int N_  = 32768;        // T*H*W
constexpr int HD_ = 4;            // heads
constexpr int F_  = 110;          // NB_FEAT
constexpr int BH_ = B_*HD_;       // 32
constexpr int FS_ = 112;          // padded feature stride
constexpr int KVS_ = 36;          // padded k/v row stride (16B-aligned; slot [32] = z parking)
constexpr int QTS_ = 29;          // qT row stride
constexpr int LAST0_ = 31744;     // first token of last time slice (31*1024)
constexpr float DN_    = 0.42044820762685725f;   // 32^-0.25
constexpr float DN2_   = 0.17677669529663687f;   // 32^-0.5
constexpr float RATIO_ = 0.09534625892455922f;   // 110^-0.5
constexpr float L2E_   = 1.4426950408889634f;    // log2(e)

// workspace layout (floats)
constexpr size_t OFF_TOKL = 0;                      // [8][1024][32]      = 262144
constexpr size_t OFF_S    = 262144;                 // [32][110*32]       = 112640
constexpr size_t OFF_Z    = OFF_S + 112640;         // [32][110]          = 3520
constexpr size_t OFF_GS   = OFF_Z + 3520;           // [32][8][110*32]    = 901120
constexpr size_t OFF_GZ   = OFF_GS + 901120;        // [32][8][110]       = 28160
constexpr size_t OFF_KM   = OFF_GZ + 28160;         // [32] unsigned
constexpr size_t WS_FLOATS = OFF_KM + 64;
constexpr size_t WS_NEED   = WS_FLOATS*4 + 256;     // ~5.24 MB

__device__ inline float fexp(float v){ return __builtin_amdgcn_exp2f(v * L2E_); }

__device__ inline float dot4(const float4 a, const float4 b){
  return a.x*b.x + a.y*b.y + a.z*b.z + a.w*b.w;
}
__device__ inline void fma4(float4& a, float s, const float4 b){
  a.x += s*b.x; a.y += s*b.y; a.z += s*b.z; a.w += s*b.w;
}
__device__ inline float dotreg(const float* h, const float4* w){
  float s = 0.f;
  #pragma unroll
  for (int t=0;t<8;++t){
    float4 ww = w[t];
    s += h[4*t+0]*ww.x + h[4*t+1]*ww.y + h[4*t+2]*ww.z + h[4*t+3]*ww.w;
  }
  return s;
}
__device__ inline unsigned f2key(float f){
  unsigned u = __float_as_uint(f);
  return (u & 0x80000000u) ? ~u : (u | 0x80000000u);
}
__device__ inline float key2f(unsigned k){
  unsigned u = (k & 0x80000000u) ? (k & 0x7FFFFFFFu) : ~k;
  return __uint_as_float(u);
}

// recompute token row from x (1x1 conv) and layernorm it -> h_[32]
__device__ inline void tok_ln_row(const float* __restrict__ x, int b, int p,
                                  const float* __restrict__ pw, const float* __restrict__ pb,
                                  const float* __restrict__ g, const float* __restrict__ bb,
                                  float* h_){
  float x0 = x[(size_t)(b*3+0)*N_ + p];
  float x1 = x[(size_t)(b*3+1)*N_ + p];
  float x2 = x[(size_t)(b*3+2)*N_ + p];
  float mean = 0.f;
  #pragma unroll
  for (int c=0;c<32;++c){
    float v = pb[c] + x0*pw[c*3+0] + x1*pw[c*3+1] + x2*pw[c*3+2];
    h_[c] = v; mean += v;
  }
  mean *= (1.f/32.f);
  float var = 0.f;
  #pragma unroll
  for (int c=0;c<32;++c){ float d = h_[c]-mean; var += d*d; }
  var *= (1.f/32.f);
  float rs = rsqrtf(var + 1e-5f);
  #pragma unroll
  for (int c=0;c<32;++c) h_[c] = (h_[c]-mean)*rs*g[c] + bb[c];
}

// ---- gate fallback: finite zero output ----
__global__ void k_out_zero(float* __restrict__ out){ if (threadIdx.x < 8) out[threadIdx.x] = 0.f; }

// ---- zero-fill ----
__global__ void k_zero(float* __restrict__ p, int n){
  int i = blockIdx.x*256 + threadIdx.x;
  if (i < n) p[i] = 0.f;
}

__global__ void k_kmax_init(unsigned* km){ if (threadIdx.x < BH_) km[threadIdx.x] = f2key(-1e30f); }

// ---- 1. global max: two-phase LDS, 2 f/lane, 4-way row split ----
__global__ void __launch_bounds__(256,2)
k_kmax(const float* __restrict__ x, const float* __restrict__ proj,
       const float* __restrict__ pw, const float* __restrict__ pb,
       const float* __restrict__ ln1g, const float* __restrict__ ln1b,
       const float* __restrict__ wk, const float* __restrict__ bk,
       unsigned* __restrict__ km){
  __shared__ float wkS[1024];      // 4 KB
  __shared__ float kL[128*KVS_];   // 18.4 KB
  __shared__ float red[256];
  int tid = threadIdx.x;
  int bh = blockIdx.x >> 5; int slab = blockIdx.x & 31;
  int b = bh >> 2, hh = bh & 3;
  for (int t=tid; t<1024; t+=256) wkS[t] = wk[hh*1024 + t];
  __syncthreads();
  int i = tid >> 1, half = tid & 1;       // phase 1: 2 lanes/token
  int w = tid >> 6, l = tid & 63;         // phase 2: wave=row quarter, lane=f pair
  int row0 = w*32;
  bool f1ok = (l < F_-64);                // l+64 < 110
  int fA = l, fB = f1ok ? (l+64) : 0;
  float mx = -1e30f;
  for (int it=0; it<8; ++it){
    int p = slab*1024 + it*128 + i;
    { // phase 1: k rows -> LDS (float4 writes)
      float h_[32];
      tok_ln_row(x, b, p, pw, pb, ln1g, ln1b, h_);
      float4* kw = (float4*)(kL + i*KVS_ + half*16);
      #pragma unroll
      for (int t4=0; t4<4; ++t4){
        float kq[4];
        #pragma unroll
        for (int u=0; u<4; ++u){
          int d = half*16 + t4*4 + u;
          kq[u] = bk[hh*32+d] + dotreg(h_, (const float4*)(wkS + d*32));
        }
        kw[t4] = make_float4(kq[0],kq[1],kq[2],kq[3]);
      }
    }
    __syncthreads();
    { // phase 2: each wave reads its 32 rows once, 2 f per lane
      float4 prA[8], prB[8];
      const float4* pga = (const float4*)(proj + (size_t)fA*32);
      const float4* pgb = (const float4*)(proj + (size_t)fB*32);
      #pragma unroll
      for (int t=0;t<8;++t){ prA[t]=pga[t]; prB[t]=pgb[t]; }
      for (int ii=row0; ii<row0+32; ++ii){
        const float4* krow = (const float4*)(kL + ii*KVS_);
        float a0=0.f,a1=0.f,a2=0.f,a3=0.f, b0=0.f,b1=0.f,b2=0.f,b3=0.f;
        #pragma unroll
        for (int t=0;t<8;++t){
          float4 kk=krow[t];
          a0 += kk.x*prA[t].x; a1 += kk.y*prA[t].y; a2 += kk.z*prA[t].z; a3 += kk.w*prA[t].w;
          b0 += kk.x*prB[t].x; b1 += kk.y*prB[t].y; b2 += kk.z*prB[t].z; b3 += kk.w*prB[t].w;
        }
        mx = fmaxf(mx, (a0+a1)+(a2+a3));
        if (f1ok) mx = fmaxf(mx, (b0+b1)+(b2+b3));
      }
    }
    __syncthreads();
  }
  red[tid] = mx*DN_; __syncthreads();
  for (int s=128; s>0; s>>=1){
    if (tid < s) red[tid] = fmaxf(red[tid], red[tid+s]);
    __syncthreads();
  }
  if (tid==0) atomicMax(&km[bh], f2key(red[0]));
}

// ---- 2. prefix state: 2 f/lane, 4-way row split; residency-3 bounds ----
__global__ void __launch_bounds__(256,3)
k_state(const float* __restrict__ x, const float* __restrict__ proj,
        const unsigned* __restrict__ km,
        const float* __restrict__ pw, const float* __restrict__ pb,
        const float* __restrict__ ln1g, const float* __restrict__ ln1b,
        const float* __restrict__ wk, const float* __restrict__ bk,
        const float* __restrict__ wv, const float* __restrict__ bv,
        float* __restrict__ S, float* __restrict__ z, int zr){
  __shared__ float wkS[1024];      // 4 KB
  __shared__ float wvS[1024];      // 4 KB
  __shared__ float kL[128*KVS_];   // 18.4 KB
  __shared__ float vL[128*KVS_];   // 18.4 KB
  __shared__ float dgL[128];
  int tid = threadIdx.x;
  int bh = blockIdx.x / 31, slice = blockIdx.x - bh*31;
  int b = bh >> 2, hh = bh & 3;
  float M = key2f(km[bh]);
  for (int t=tid; t<1024; t+=256){ wkS[t] = wk[hh*1024 + t]; wvS[t] = wv[hh*1024 + t]; }
  __syncthreads();
  int i = tid >> 1, half = tid & 1;       // phase 1: 2 lanes/token
  int w = tid >> 6, l = tid & 63;         // phase 2: wave=row quarter, lane=f pair
  int row0 = w*32;
  bool f1ok = (l < F_-64);
  int fA = l, fB = f1ok ? (l+64) : 0;
  float4 accA[8], accB[8]; float zA = 0.f, zB = 0.f;
  #pragma unroll
  for (int t=0;t<8;++t){ accA[t]=make_float4(0,0,0,0); accB[t]=make_float4(0,0,0,0); }
  for (int it=0; it<8; ++it){
    int p = slice*1024 + it*128 + i;
    { // phase 1: float4 writes
      float h_[32];
      tok_ln_row(x, b, p, pw, pb, ln1g, ln1b, h_);
      float dgp = 0.f;
      float4* kw = (float4*)(kL + i*KVS_ + half*16);
      float4* vw = (float4*)(vL + i*KVS_ + half*16);
      #pragma unroll
      for (int t4=0; t4<4; ++t4){
        float kq[4], vq[4];
        #pragma unroll
        for (int u=0; u<4; ++u){
          int d = half*16 + t4*4 + u;
          kq[u] = bk[hh*32+d] + dotreg(h_, (const float4*)(wkS + d*32));
          dgp += kq[u]*kq[u];
          vq[u] = bv[hh*32+d] + dotreg(h_, (const float4*)(wvS + d*32));
        }
        kw[t4] = make_float4(kq[0],kq[1],kq[2],kq[3]);
        vw[t4] = make_float4(vq[0],vq[1],vq[2],vq[3]);
      }
      dgp += __shfl_xor(dgp, 1, 64);
      if (half==0) dgL[i] = 0.5f*DN2_*dgp;
    }
    __syncthreads();
    { // phase 2: pr loads indexed by (f + zr*it) so they can't be hoisted
      float4 prA[8], prB[8];
      const float4* pga = (const float4*)(proj + (size_t)(fA + zr*it)*32);
      const float4* pgb = (const float4*)(proj + (size_t)(fB + zr*it)*32);
      #pragma unroll
      for (int t=0;t<8;++t){ prA[t]=pga[t]; prB[t]=pgb[t]; }
      for (int ii=row0; ii<row0+32; ++ii){
        const float4* krow = (const float4*)(kL + ii*KVS_);
        float a0=0.f,a1=0.f,a2=0.f,a3=0.f, b0=0.f,b1=0.f,b2=0.f,b3=0.f;
        #pragma unroll
        for (int t=0;t<8;++t){
          float4 kk=krow[t];
          a0 += kk.x*prA[t].x; a1 += kk.y*prA[t].y; a2 += kk.z*prA[t].z; a3 += kk.w*prA[t].w;
          b0 += kk.x*prB[t].x; b1 += kk.y*prB[t].y; b2 += kk.z*prB[t].z; b3 += kk.w*prB[t].w;
        }
        float dg = dgL[ii];
        float kpA = RATIO_*(fexp(((a0+a1)+(a2+a3))*DN_ - dg - M) + 1e-4f);
        float kpB = f1ok ? RATIO_*(fexp(((b0+b1)+(b2+b3))*DN_ - dg - M) + 1e-4f) : 0.f;
        zA += kpA; zB += kpB;
        const float4* vrow = (const float4*)(vL + ii*KVS_);
        #pragma unroll
        for (int t=0;t<8;++t){
          float4 vv = vrow[t];
          fma4(accA[t], kpA, vv);
          fma4(accB[t], kpB, vv);
        }
      }
    }
    __syncthreads();
  }
  // ---- combine 4 wave-partials per f ----
  if (w==1 || w==3){
    int r = (w==1) ? l : (64+l);
    float* rowA = kL + r*KVS_;
    #pragma unroll
    for (int t=0;t<8;++t){
      rowA[4*t+0]=accA[t].x; rowA[4*t+1]=accA[t].y; rowA[4*t+2]=accA[t].z; rowA[4*t+3]=accA[t].w;
    }
    rowA[32] = zA;
    if (f1ok){
      float* rowB = vL + r*KVS_;
      #pragma unroll
      for (int t=0;t<8;++t){
        rowB[4*t+0]=accB[t].x; rowB[4*t+1]=accB[t].y; rowB[4*t+2]=accB[t].z; rowB[4*t+3]=accB[t].w;
      }
      rowB[32] = zB;
    }
  }
  __syncthreads();
  if (w==0 || w==2){
    int r = (w==0) ? l : (64+l);
    const float* rowA = kL + r*KVS_;
    #pragma unroll
    for (int t=0;t<8;++t){
      accA[t].x += rowA[4*t+0]; accA[t].y += rowA[4*t+1];
      accA[t].z += rowA[4*t+2]; accA[t].w += rowA[4*t+3];
    }
    zA += rowA[32];
    if (f1ok){
      const float* rowB = vL + r*KVS_;
      #pragma unroll
      for (int t=0;t<8;++t){
        accB[t].x += rowB[4*t+0]; accB[t].y += rowB[4*t+1];
        accB[t].z += rowB[4*t+2]; accB[t].w += rowB[4*t+3];
      }
      zB += rowB[32];
    }
  }
  __syncthreads();
  if (w==2){
    float* rowA = kL + l*KVS_;
    #pragma unroll
    for (int t=0;t<8;++t){
      rowA[4*t+0]=accA[t].x; rowA[4*t+1]=accA[t].y; rowA[4*t+2]=accA[t].z; rowA[4*t+3]=accA[t].w;
    }
    rowA[32] = zA;
    if (f1ok){
      float* rowB = vL + l*KVS_;
      #pragma unroll
      for (int t=0;t<8;++t){
        rowB[4*t+0]=accB[t].x; rowB[4*t+1]=accB[t].y; rowB[4*t+2]=accB[t].z; rowB[4*t+3]=accB[t].w;
      }
      rowB[32] = zB;
    }
  }
  __syncthreads();
  if (w==0){
    const float* rowA = kL + l*KVS_;
    float* soA = S + (size_t)bh*3520 + (size_t)fA*32;
    #pragma unroll
    for (int t=0;t<8;++t){
      atomicAdd(soA + 4*t+0, accA[t].x + rowA[4*t+0]);
      atomicAdd(soA + 4*t+1, accA[t].y + rowA[4*t+1]);
      atomicAdd(soA + 4*t+2, accA[t].z + rowA[4*t+2]);
      atomicAdd(soA + 4*t+3, accA[t].w + rowA[4*t+3]);
    }
    atomicAdd(z + (size_t)bh*F_ + fA, zA + rowA[32]);
    if (f1ok){
      const float* rowB = vL + l*KVS_;
      float* soB = S + (size_t)bh*3520 + (size_t)(l+64)*32;
      #pragma unroll
      for (int t=0;t<8;++t){
        atomicAdd(soB + 4*t+0, accB[t].x + rowB[4*t+0]);
        atomicAdd(soB + 4*t+1, accB[t].y + rowB[4*t+1]);
        atomicAdd(soB + 4*t+2, accB[t].z + rowB[4*t+2]);
        atomicAdd(soB + 4*t+3, accB[t].w + rowB[4*t+3]);
      }
      atomicAdd(z + (size_t)bh*F_ + l+64, zB + rowB[32]);
    }
  }
}

// ---- 3. per-group sums over last-slice tokens (groups of 128) ----
__global__ void __launch_bounds__(256,2)
k_gsum_last(const float* __restrict__ x, const float* __restrict__ proj,
            const unsigned* __restrict__ km,
            const float* __restrict__ pw, const float* __restrict__ pb,
            const float* __restrict__ ln1g, const float* __restrict__ ln1b,
            const float* __restrict__ wk, const float* __restrict__ bk,
            const float* __restrict__ wv, const float* __restrict__ bv,
            float* __restrict__ gs, float* __restrict__ gz){
  __shared__ float wkS[1024];
  __shared__ float wvS[1024];
  __shared__ float kL[128*KVS_];
  __shared__ float vL[128*KVS_];
  __shared__ float dgL[128];
  int tid = threadIdx.x;
  int bh = blockIdx.x >> 3, g = blockIdx.x & 7;
  int b = bh >> 2, hh = bh & 3;
  float M = key2f(km[bh]);
  for (int t=tid; t<1024; t+=256){ wkS[t] = wk[hh*1024 + t]; wvS[t] = wv[hh*1024 + t]; }
  __syncthreads();
  int i = tid >> 1, half = tid & 1;
  {
    int p = LAST0_ + g*128 + i;
    float h_[32];
    tok_ln_row(x, b, p, pw, pb, ln1g, ln1b, h_);
    float dgp = 0.f;
    float4* kw = (float4*)(kL + i*KVS_ + half*16);
    float4* vw = (float4*)(vL + i*KVS_ + half*16);
    #pragma unroll
    for (int t4=0; t4<4; ++t4){
      float kq[4], vq[4];
      #pragma unroll
      for (int u=0; u<4; ++u){
        int d = half*16 + t4*4 + u;
        kq[u] = bk[hh*32+d] + dotreg(h_, (const float4*)(wkS + d*32));
        dgp += kq[u]*kq[u];
        vq[u] = bv[hh*32+d] + dotreg(h_, (const float4*)(wvS + d*32));
      }
      kw[t4] = make_float4(kq[0],kq[1],kq[2],kq[3]);
      vw[t4] = make_float4(vq[0],vq[1],vq[2],vq[3]);
    }
    dgp += __shfl_xor(dgp, 1, 64);
    if (half==0) dgL[i] = 0.5f*DN2_*dgp;
  }
  __syncthreads();
  if (tid < F_){
    float4 pr[8];
    const float4* pg = (const float4*)(proj + (size_t)tid*32);
    #pragma unroll
    for (int t=0;t<8;++t) pr[t]=pg[t];
    float4 acc[8]; float zacc = 0.f;
    #pragma unroll
    for (int t=0;t<8;++t) acc[t]=make_float4(0,0,0,0);
    #pragma unroll 2
    for (int ii=0; ii<128; ++ii){
      const float4* krow = (const float4*)(kL + ii*KVS_);
      float dd0=0.f, dd1=0.f, dd2=0.f, dd3=0.f;
      #pragma unroll
      for (int t=0;t<8;++t){
        float4 kk=krow[t], pp=pr[t];
        dd0 += kk.x*pp.x; dd1 += kk.y*pp.y;
        dd2 += kk.z*pp.z; dd3 += kk.w*pp.w;
      }
      float dd = (dd0+dd1)+(dd2+dd3);
      float kp = RATIO_*(fexp(dd*DN_ - dgL[ii] - M) + 1e-4f);
      zacc += kp;
      const float4* vrow = (const float4*)(vL + ii*KVS_);
      #pragma unroll
      for (int t=0;t<8;++t) fma4(acc[t], kp, vrow[t]);
    }
    float4* o = (float4*)(gs + (size_t)blockIdx.x*3520 + tid*32);
    #pragma unroll
    for (int t=0;t<8;++t) o[t]=acc[t];
    gz[(size_t)blockIdx.x*F_ + tid] = zacc;
  }
}

// ---- 4. exclusive prefix over the 8 groups, seeded with global S ----
__global__ void k_scan_last(const float* __restrict__ S, const float* __restrict__ z,
                            float* __restrict__ gs, float* __restrict__ gz){
  int bh = blockIdx.x;
  for (int t=threadIdx.x; t<3630; t+=256){
    if (t < 3520){
      float carry = S[(size_t)bh*3520 + t];
      size_t base = (size_t)bh*8*3520 + t;
      for (int g=0; g<8; ++g){
        size_t idx = base + (size_t)g*3520;
        float tv = gs[idx]; gs[idx] = carry; carry += tv;
      }
    } else {
      int f = t - 3520;
      float carry = z[(size_t)bh*F_ + f];
      size_t base = (size_t)bh*8*F_ + f;
      for (int g=0; g<8; ++g){
        size_t idx = base + (size_t)g*F_;
        float tv = gz[idx]; gz[idx] = carry; carry += tv;
      }
    }
  }
}

// ---- 5. tok_last = preproc(last slice) + bo ----
__global__ void k_preproc_last(const float* __restrict__ x, const float* __restrict__ pw,
                               const float* __restrict__ pb, const float* __restrict__ bo,
                               float* __restrict__ tokl){
  int gid = blockIdx.x*256 + threadIdx.x;   // 262144
  int c = gid & 31; int idx = gid >> 5;
  int b = idx >> 10, i = idx & 1023;
  int p = LAST0_ + i;
  const float* xb = x + (size_t)b*3*N_ + p;
  float s = pb[c] + bo[c];
  s += xb[0]           * pw[c*3+0];
  s += xb[(size_t)N_]  * pw[c*3+1];
  s += xb[(size_t)2*N_]* pw[c*3+2];
  tokl[(size_t)gid] = s;
}

// ---- 6. intra attention: feature-split causal loop, bounded-unroll feature gen ----
__global__ void __launch_bounds__(256,1)
k_intra_last(const float* __restrict__ x, const float* __restrict__ proj,
             const unsigned* __restrict__ km,
             const float* __restrict__ pw, const float* __restrict__ pb,
             const float* __restrict__ ln1g, const float* __restrict__ ln1b,
             const float* __restrict__ wq, const float* __restrict__ bq,
             const float* __restrict__ wk, const float* __restrict__ bk,
             const float* __restrict__ wv, const float* __restrict__ bv,
             const float* __restrict__ wo,
             const float* __restrict__ gs, const float* __restrict__ gz,
             float* __restrict__ tokl){
  __shared__ float kpS[64*FS_];   // 28 KB
  __shared__ float vS[64*32];     // 8 KB
  __shared__ float SL[FS_*32];    // 14 KB
  __shared__ float zL[FS_];       // 0.45 KB
  __shared__ float woS[32*32];    // 4 KB : woS[c][d] = wo[c][hh*32+d]
  __shared__ float qT[64*QTS_];   // 7.25 KB : raw q dd staging
  int tid = threadIdx.x;
  int bh = blockIdx.x >> 3, g = blockIdx.x & 7;
  int b = bh >> 2, hh = bh & 3;
  float M = key2f(km[bh]);
  for (int t=tid; t<FS_*32; t+=256) SL[t] = (t < 3520) ? gs[(size_t)blockIdx.x*3520 + t] : 0.f;
  for (int t=tid; t<FS_; t+=256)    zL[t] = (t < F_)   ? gz[(size_t)blockIdx.x*F_ + t] : 0.f;
  for (int t=tid; t<1024; t+=256){ int c = t >> 5, d = t & 31; woS[t] = wo[c*128 + hh*32 + d]; }
  int r = tid >> 2, q = tid & 3;
  int f0 = q*28, e0 = q*8;
  __syncthreads();
  for (int s=0; s<2; ++s){
    int iloc = g*128 + s*64 + r;
    int p = LAST0_ + iloc;
    float q0v[28];
    // ---- feature phase (bounded-unroll global loads) ----
    {
      float h_[32];
      tok_ln_row(x, b, p, pw, pb, ln1g, ln1b, h_);
      { // K features for own f-range -> kpS (LDS dest; rolled loop OK)
        float kr[32]; float kdg = 0.f;
        #pragma unroll
        for (int d=0; d<32; ++d){
          kr[d] = bk[hh*32+d] + dotreg(h_, (const float4*)(wk + (size_t)(hh*32+d)*32));
          kdg += kr[d]*kr[d];
        }
        kdg *= 0.5f*DN2_;
        #pragma unroll 4
        for (int t=0; t<28; ++t){
          int f = f0 + t; float kp = 0.f;
          if (f < F_){
            float dd = dotreg(kr, (const float4*)(proj + (size_t)f*32));
            kp = RATIO_*(fexp(dd*DN_ - kdg - M) + 1e-4f);
          }
          kpS[r*FS_+f] = kp;
        }
      }
      // V for own e-range
      #pragma unroll
      for (int d0=0; d0<8; ++d0){
        int d = e0 + d0;
        vS[r*32+d] = bv[hh*32+d] + dotreg(h_, (const float4*)(wv + (size_t)(hh*32+d)*32));
      }
      { // Q features: rolled dd -> qT (LDS), then unrolled LDS->reg exp
        float qr_[32]; float qdg = 0.f;
        #pragma unroll
        for (int d=0; d<32; ++d){
          qr_[d] = bq[hh*32+d] + dotreg(h_, (const float4*)(wq + (size_t)(hh*32+d)*32));
          qdg += qr_[d]*qr_[d];
        }
        qdg *= 0.5f*DN2_;
        float mxl = -1e30f;
        #pragma unroll 4
        for (int t=0; t<28; ++t){
          int f = f0 + t;
          float dd = (f < F_) ? dotreg(qr_, (const float4*)(proj + (size_t)f*32))*DN_ : -1e30f;
          qT[r*QTS_+t] = dd;
          mxl = fmaxf(mxl, dd);
        }
        mxl = fmaxf(mxl, __shfl_xor(mxl, 1, 64));
        mxl = fmaxf(mxl, __shfl_xor(mxl, 2, 64));
        #pragma unroll
        for (int t=0; t<28; ++t){
          int f = f0 + t;
          q0v[t] = (f < F_) ? RATIO_*(fexp(qT[r*QTS_+t] - qdg - mxl) + 1e-4f) : 0.f;
        }
      }
    }
    __syncthreads();
    // ---- matmul + fused wo (feature-split; shfl score combine) ----
    {
      // S part: partial over own 28 f, all 32 e
      float pacc[32];
      #pragma unroll
      for (int t=0;t<32;++t) pacc[t]=0.f;
      float dens = 0.f, sq = 0.f;
      #pragma unroll
      for (int t=0; t<28; ++t){
        int f = f0 + t; float qv = q0v[t];
        sq += qv;
        dens += qv * zL[f];
        const float4* sr = (const float4*)(SL + f*32);
        #pragma unroll
        for (int e4=0; e4<8; ++e4){
          float4 sv = sr[e4];
          pacc[e4*4+0] += qv*sv.x; pacc[e4*4+1] += qv*sv.y;
          pacc[e4*4+2] += qv*sv.z; pacc[e4*4+3] += qv*sv.w;
        }
      }
      dens += __shfl_xor(dens, 1, 64); dens += __shfl_xor(dens, 2, 64);
      sq   += __shfl_xor(sq,   1, 64); sq   += __shfl_xor(sq,   2, 64);
      // reduce-scatter pacc (xor2 halves then xor1 quarters)
      bool lo2 = ((q & 2) == 0);
      float p16[16];
      #pragma unroll
      for (int t=0;t<16;++t){
        float send = lo2 ? pacc[16+t] : pacc[t];
        float recv = __shfl_xor(send, 2, 64);
        p16[t] = (lo2 ? pacc[t] : pacc[16+t]) + recv;
      }
      bool lo1 = ((q & 1) == 0);
      float4 accA, accB;
      {
        float e8[8];
        #pragma unroll
        for (int t=0;t<8;++t){
          float send = lo1 ? p16[8+t] : p16[t];
          float recv = __shfl_xor(send, 1, 64);
          e8[t] = (lo1 ? p16[t] : p16[8+t]) + recv;
        }
        accA = make_float4(e8[0],e8[1],e8[2],e8[3]);
        accB = make_float4(e8[4],e8[5],e8[6],e8[7]);
      }
      float den = dens;
      // causal j loop: each thread covers its 28 features, shfl-combine score
      for (int j=0; j<=r; ++j){
        const float4* k4 = (const float4*)(kpS + j*FS_ + f0);
        float a0=0.f, a1=0.f, a2=0.f, a3=0.f;
        #pragma unroll
        for (int t4=0; t4<7; ++t4){
          float4 kk = k4[t4];
          a0 += q0v[4*t4+0]*kk.x; a1 += q0v[4*t4+1]*kk.y;
          a2 += q0v[4*t4+2]*kk.z; a3 += q0v[4*t4+3]*kk.w;
        }
        float a = (a0+a1)+(a2+a3);
        a += __shfl_xor(a, 1, 64);
        a += __shfl_xor(a, 2, 64);
        den += a;
        const float4* vv = (const float4*)(vS + j*32 + e0);
        fma4(accA, a, vv[0]); fma4(accB, a, vv[1]);
      }
      den += 1e-6f*sq;
      float dinv = 1.f/den;
      float ao8[8] = { accA.x*dinv, accA.y*dinv, accA.z*dinv, accA.w*dinv,
                       accB.x*dinv, accB.y*dinv, accB.z*dinv, accB.w*dinv };
      // wo epilogue: rolling per-c shfl-reduce; keep only own 8 outputs
      float own[8];
      #pragma unroll
      for (int c=0; c<32; ++c){
        float s2 = 0.f;
        #pragma unroll
        for (int t=0; t<8; ++t) s2 += ao8[t]*woS[c*32 + e0 + t];
        s2 += __shfl_xor(s2, 1, 64);
        s2 += __shfl_xor(s2, 2, 64);
        if ((c >> 3) == q) own[c & 7] = s2;
      }
      float* dst = tokl + ((size_t)b*1024 + iloc)*32;
      #pragma unroll
      for (int t=0; t<8; ++t) atomicAdd(dst + q*8 + t, own[t]);
    }
    __syncthreads();
    // ---- carry update between sub-chunks ----
    if (s == 0){
      for (int t=tid; t<3520; t+=256){
        int f = t >> 5, e = t & 31;
        float ssum0 = 0.f, ssum1 = 0.f;
        for (int jj=0; jj<64; jj+=2){
          ssum0 += kpS[jj*FS_+f]*vS[jj*32+e];
          ssum1 += kpS[(jj+1)*FS_+f]*vS[(jj+1)*32+e];
        }
        SL[t] += ssum0 + ssum1;
      }
      for (int t=tid; t<F_; t+=256){
        float ssum0 = 0.f, ssum1 = 0.f;
        for (int jj=0; jj<64; jj+=2){
          ssum0 += kpS[jj*FS_+t];
          ssum1 += kpS[(jj+1)*FS_+t];
        }
        zL[t] += ssum0 + ssum1;
      }
      __syncthreads();
    }
  }
}

// ---- 7. fused LN2 + FF + residual on last slice ----
__global__ void __launch_bounds__(256,1)
k_ff_last(float* __restrict__ tok,
          const float* __restrict__ ln2g, const float* __restrict__ ln2b,
          const float* __restrict__ w1, const float* __restrict__ b1,
          const float* __restrict__ w2, const float* __restrict__ b2){
  __shared__ float w1s[128*32];
  __shared__ float w2t[128*32];
  __shared__ float b1s[128];
  __shared__ float b2s[32];
  __shared__ float lg[32], lb[32];
  int tid = threadIdx.x;
  for (int t=tid; t<4096; t+=256){
    w1s[t] = w1[t];
    int j = t >> 5, c = t & 31;
    w2t[t] = w2[c*128 + j];
  }
  if (tid < 128) b1s[tid] = b1[tid];
  if (tid < 32){ b2s[tid] = b2[tid]; lg[tid] = ln2g[tid]; lb[tid] = ln2b[tid]; }
  __syncthreads();
  size_t bp = (size_t)blockIdx.x*256 + tid;
  float* rowp = tok + bp*32;
  float r_[32], h_[32];
  { const float4* tr = (const float4*)rowp;
    float mean = 0.f;
    #pragma unroll
    for (int t=0;t<8;++t){
      float4 v = tr[t];
      r_[4*t+0]=v.x; r_[4*t+1]=v.y; r_[4*t+2]=v.z; r_[4*t+3]=v.w;
      mean += v.x+v.y+v.z+v.w;
    }
    mean *= (1.f/32.f);
    float var = 0.f;
    #pragma unroll
    for (int t=0;t<32;++t){ float d=r_[t]-mean; var += d*d; }
    var *= (1.f/32.f);
    float rs = rsqrtf(var + 1e-5f);
    #pragma unroll
    for (int t=0;t<32;++t) h_[t] = (r_[t]-mean)*rs*lg[t] + lb[t];
  }
  float4 o[8];
  { const float4* bb = (const float4*)b2s;
    #pragma unroll
    for (int t=0;t<8;++t) o[t]=bb[t]; }
  for (int j=0; j<128; ++j){
    float a = b1s[j] + dotreg(h_, (const float4*)(w1s + j*32));
    float gl = 0.5f*a*(1.f + erff(a*0.70710678118654752f));
    const float4* wr = (const float4*)(w2t + j*32);
    #pragma unroll
    for (int t=0;t<8;++t) fma4(o[t], gl, wr[t]);
  }
  #pragma unroll
  for (int t=0;t<8;++t){
    float4 wv2;
    wv2.x = r_[4*t+0] + o[t].x;
    wv2.y = r_[4*t+1] + o[t].y;
    wv2.z = r_[4*t+2] + o[t].z;
    wv2.w = r_[4*t+3] + o[t].w;
    ((float4*)rowp)[t] = wv2;
  }
}

// ---- 8. readout ----
__global__ void k_readout(const float* __restrict__ tokl, const float* __restrict__ xin,
                          const float* __restrict__ tcw, const float* __restrict__ tcb,
                          const float* __restrict__ row, const float* __restrict__ rob,
                          float* __restrict__ out){
  __shared__ float red[256];
  int b = blockIdx.x; int tid = threadIdx.x;
  float acc = 0.f;
  for (int it=0; it<4; ++it){
    int px = it*256 + tid;
    int y = px >> 5, xx = px & 31;
    float s = 0.f;
    for (int ic=0; ic<33; ++ic){
      for (int ky=0; ky<5; ++ky){
        int yy = y + ky - 2; if (yy < 0 || yy >= 32) continue;
        for (int kx=0; kx<5; ++kx){
          int xc = xx + kx - 2; if (xc < 0 || xc >= 32) continue;
          float v;
          if (ic < 32) v = tokl[((size_t)b*1024 + yy*32 + xc)*32 + ic];
          else         v = xin[((size_t)b*3 + 2)*N_ + yy*32 + xc];
          s += v * tcw[(ic*5+ky)*5+kx];
        }
      }
    }
    acc += s;
  }
  red[tid] = acc; __syncthreads();
  for (int st=128; st>0; st>>=1){
    if (tid < st) red[tid] += red[tid+st];
    __syncthreads();
  }
  if (tid==0) out[b] = (red[0]*(1.f/1024.f) + tcb[0]) * row[0] + rob[0];
}

extern "C" void kernel_launch(void* const* d_in, const int* in_sizes, int n_in,
                              void* d_out, int out_size, void* d_ws, size_t ws_size,
                              hipStream_t stream){
  const float* x    = (const float*)d_in[0];
  const float* pw   = (const float*)d_in[1];
  const float* pb   = (const float*)d_in[2];
  const float* ln1g = (const float*)d_in[3];
  const float* ln1b = (const float*)d_in[4];
  const float* wq   = (const float*)d_in[5];
  const float* bq   = (const float*)d_in[6];
  const float* wk   = (const float*)d_in[7];
  const float* bk   = (const float*)d_in[8];
  const float* wv   = (const float*)d_in[9];
  const float* bv   = (const float*)d_in[10];
  const float* proj = (const float*)d_in[11];
  const float* wo   = (const float*)d_in[12];
  const float* bo   = (const float*)d_in[13];
  const float* ln2g = (const float*)d_in[14];
  const float* ln2b = (const float*)d_in[15];
  const float* ffw1 = (const float*)d_in[16];
  const float* ffb1 = (const float*)d_in[17];
  const float* ffw2 = (const float*)d_in[18];
  const float* ffb2 = (const float*)d_in[19];
  const float* tcw  = (const float*)d_in[20];
  const float* tcb  = (const float*)d_in[21];
  const float* row_ = (const float*)d_in[22];
  const float* rob  = (const float*)d_in[23];

  float* ws   = (float*)d_ws;
  float* tokl = ws + OFF_TOKL;
  float* S    = ws + OFF_S;
  float* z    = ws + OFF_Z;
  float* gs   = ws + OFF_GS;
  float* gz   = ws + OFF_GZ;
  unsigned* km = (unsigned*)(ws + OFF_KM);

  if (ws_size < WS_NEED){
    k_out_zero<<<1, 64, 0, stream>>>((float*)d_out);
    return;
  }
  int zr = (int)(ws_size >> 62);   // runtime 0, opaque to the compiler

  k_zero<<<(112640+3520+255)/256, 256, 0, stream>>>(S, 112640+3520);  // S and z contiguous
  k_kmax_init<<<1, 64, 0, stream>>>(km);
  k_kmax<<<BH_*32, 256, 0, stream>>>(x, proj, pw, pb, ln1g, ln1b, wk, bk, km);
  k_state<<<BH_*31, 256, 0, stream>>>(x, proj, km, pw, pb, ln1g, ln1b, wk, bk, wv, bv, S, z, zr);
  k_gsum_last<<<BH_*8, 256, 0, stream>>>(x, proj, km, pw, pb, ln1g, ln1b, wk, bk, wv, bv, gs, gz);
  k_scan_last<<<BH_, 256, 0, stream>>>(S, z, gs, gz);
  k_preproc_last<<<1024, 256, 0, stream>>>(x, pw, pb, bo, tokl);
  k_intra_last<<<BH_*8, 256, 0, stream>>>(x, proj, km, pw, pb, ln1g, ln1b,
                                          wq, bq, wk, bk, wv, bv, wo, gs, gz, tokl);
  k_ff_last<<<32, 256, 0, stream>>>(tokl, ln2g, ln2b, ffw1, ffb1, ffw2, ffb2);
  k_readout<<<B_, 256, 0, stream>>>(tokl, x, tcw, tcb, row_, rob, (float*)d_out);
}

// Round 24
// 1895.998 us; speedup vs baseline: 1.9035x; 1.9035x over previous
//
#include <hip/hip_runtime.h>
#include <math.h>

// ---- problem constants ----
constexpr int B_  = 8;
constexpr int N_  = 32768;        // T*H*W
constexpr int HD_ = 4;            // heads
constexpr int F_  = 110;          // NB_FEAT
constexpr int BH_ = B_*HD_;       // 32
constexpr int FS_ = 112;          // padded feature stride
constexpr int KVS_ = 36;          // padded k/v row stride (16B-aligned; slot [32] = z parking)
constexpr int QTS_ = 29;          // qT row stride
constexpr int LAST0_ = 31744;     // first token of last time slice (31*1024)
constexpr float DN_    = 0.42044820762685725f;   // 32^-0.25
constexpr float DN2_   = 0.17677669529663687f;   // 32^-0.5
constexpr float RATIO_ = 0.09534625892455922f;   // 110^-0.5
constexpr float L2E_   = 1.4426950408889634f;    // log2(e)

// workspace layout (floats)
constexpr size_t OFF_TOKL = 0;                      // [8][1024][32]      = 262144
constexpr size_t OFF_S    = 262144;                 // [32][110*32]       = 112640
constexpr size_t OFF_Z    = OFF_S + 112640;         // [32][110]          = 3520
constexpr size_t OFF_GS   = OFF_Z + 3520;           // [32][8][110*32]    = 901120
constexpr size_t OFF_GZ   = OFF_GS + 901120;        // [32][8][110]       = 28160
constexpr size_t OFF_KM   = OFF_GZ + 28160;         // [32] unsigned
constexpr size_t WS_FLOATS = OFF_KM + 64;
constexpr size_t WS_NEED   = WS_FLOATS*4 + 256;     // ~5.24 MB

__device__ inline float fexp(float v){ return __builtin_amdgcn_exp2f(v * L2E_); }

__device__ inline float dot4(const float4 a, const float4 b){
  return a.x*b.x + a.y*b.y + a.z*b.z + a.w*b.w;
}
__device__ inline void fma4(float4& a, float s, const float4 b){
  a.x += s*b.x; a.y += s*b.y; a.z += s*b.z; a.w += s*b.w;
}
__device__ inline float dotreg(const float* h, const float4* w){
  float s = 0.f;
  #pragma unroll
  for (int t=0;t<8;++t){
    float4 ww = w[t];
    s += h[4*t+0]*ww.x + h[4*t+1]*ww.y + h[4*t+2]*ww.z + h[4*t+3]*ww.w;
  }
  return s;
}
__device__ inline unsigned f2key(float f){
  unsigned u = __float_as_uint(f);
  return (u & 0x80000000u) ? ~u : (u | 0x80000000u);
}
__device__ inline float key2f(unsigned k){
  unsigned u = (k & 0x80000000u) ? (k & 0x7FFFFFFFu) : ~k;
  return __uint_as_float(u);
}

// recompute token row from x (1x1 conv) and layernorm it -> h_[32]
__device__ inline void tok_ln_row(const float* __restrict__ x, int b, int p,
                                  const float* __restrict__ pw, const float* __restrict__ pb,
                                  const float* __restrict__ g, const float* __restrict__ bb,
                                  float* h_){
  float x0 = x[(size_t)(b*3+0)*N_ + p];
  float x1 = x[(size_t)(b*3+1)*N_ + p];
  float x2 = x[(size_t)(b*3+2)*N_ + p];
  float mean = 0.f;
  #pragma unroll
  for (int c=0;c<32;++c){
    float v = pb[c] + x0*pw[c*3+0] + x1*pw[c*3+1] + x2*pw[c*3+2];
    h_[c] = v; mean += v;
  }
  mean *= (1.f/32.f);
  float var = 0.f;
  #pragma unroll
  for (int c=0;c<32;++c){ float d = h_[c]-mean; var += d*d; }
  var *= (1.f/32.f);
  float rs = rsqrtf(var + 1e-5f);
  #pragma unroll
  for (int c=0;c<32;++c) h_[c] = (h_[c]-mean)*rs*g[c] + bb[c];
}

// ---- gate fallback: finite zero output ----
__global__ void k_out_zero(float* __restrict__ out){ if (threadIdx.x < 8) out[threadIdx.x] = 0.f; }

// ---- zero-fill ----
__global__ void k_zero(float* __restrict__ p, int n){
  int i = blockIdx.x*256 + threadIdx.x;
  if (i < n) p[i] = 0.f;
}

__global__ void k_kmax_init(unsigned* km){ if (threadIdx.x < BH_) km[threadIdx.x] = f2key(-1e30f); }

// ---- 1. global max: two-phase LDS, 2 f/lane, 4-way row split ----
__global__ void __launch_bounds__(256,2)
k_kmax(const float* __restrict__ x, const float* __restrict__ proj,
       const float* __restrict__ pw, const float* __restrict__ pb,
       const float* __restrict__ ln1g, const float* __restrict__ ln1b,
       const float* __restrict__ wk, const float* __restrict__ bk,
       unsigned* __restrict__ km){
  __shared__ float wkS[1024];      // 4 KB
  __shared__ float kL[128*KVS_];   // 18.4 KB
  __shared__ float red[256];
  int tid = threadIdx.x;
  int bh = blockIdx.x >> 5; int slab = blockIdx.x & 31;
  int b = bh >> 2, hh = bh & 3;
  for (int t=tid; t<1024; t+=256) wkS[t] = wk[hh*1024 + t];
  __syncthreads();
  int i = tid >> 1, half = tid & 1;       // phase 1: 2 lanes/token
  int w = tid >> 6, l = tid & 63;         // phase 2: wave=row quarter, lane=f pair
  int row0 = w*32;
  bool f1ok = (l < F_-64);                // l+64 < 110
  int fA = l, fB = f1ok ? (l+64) : 0;
  float mx = -1e30f;
  for (int it=0; it<8; ++it){
    int p = slab*1024 + it*128 + i;
    { // phase 1: k rows -> LDS (float4 writes)
      float h_[32];
      tok_ln_row(x, b, p, pw, pb, ln1g, ln1b, h_);
      float4* kw = (float4*)(kL + i*KVS_ + half*16);
      #pragma unroll
      for (int t4=0; t4<4; ++t4){
        float kq[4];
        #pragma unroll
        for (int u=0; u<4; ++u){
          int d = half*16 + t4*4 + u;
          kq[u] = bk[hh*32+d] + dotreg(h_, (const float4*)(wkS + d*32));
        }
        kw[t4] = make_float4(kq[0],kq[1],kq[2],kq[3]);
      }
    }
    __syncthreads();
    { // phase 2: each wave reads its 32 rows once, 2 f per lane
      float4 prA[8], prB[8];
      const float4* pga = (const float4*)(proj + (size_t)fA*32);
      const float4* pgb = (const float4*)(proj + (size_t)fB*32);
      #pragma unroll
      for (int t=0;t<8;++t){ prA[t]=pga[t]; prB[t]=pgb[t]; }
      for (int ii=row0; ii<row0+32; ++ii){
        const float4* krow = (const float4*)(kL + ii*KVS_);
        float a0=0.f,a1=0.f,a2=0.f,a3=0.f, b0=0.f,b1=0.f,b2=0.f,b3=0.f;
        #pragma unroll
        for (int t=0;t<8;++t){
          float4 kk=krow[t];
          a0 += kk.x*prA[t].x; a1 += kk.y*prA[t].y; a2 += kk.z*prA[t].z; a3 += kk.w*prA[t].w;
          b0 += kk.x*prB[t].x; b1 += kk.y*prB[t].y; b2 += kk.z*prB[t].z; b3 += kk.w*prB[t].w;
        }
        mx = fmaxf(mx, (a0+a1)+(a2+a3));
        if (f1ok) mx = fmaxf(mx, (b0+b1)+(b2+b3));
      }
    }
    __syncthreads();
  }
  red[tid] = mx*DN_; __syncthreads();
  for (int s=128; s>0; s>>=1){
    if (tid < s) red[tid] = fmaxf(red[tid], red[tid+s]);
    __syncthreads();
  }
  if (tid==0) atomicMax(&km[bh], f2key(red[0]));
}

// ---- 2. prefix state: 2 f/lane, 4-way row split; zr defeats pr-load hoisting ----
__global__ void __launch_bounds__(256,2)
k_state(const float* __restrict__ x, const float* __restrict__ proj,
        const unsigned* __restrict__ km,
        const float* __restrict__ pw, const float* __restrict__ pb,
        const float* __restrict__ ln1g, const float* __restrict__ ln1b,
        const float* __restrict__ wk, const float* __restrict__ bk,
        const float* __restrict__ wv, const float* __restrict__ bv,
        float* __restrict__ S, float* __restrict__ z, int zr){
  __shared__ float wkS[1024];      // 4 KB
  __shared__ float wvS[1024];      // 4 KB
  __shared__ float kL[128*KVS_];   // 18.4 KB
  __shared__ float vL[128*KVS_];   // 18.4 KB
  __shared__ float dgL[128];
  int tid = threadIdx.x;
  int bh = blockIdx.x / 31, slice = blockIdx.x - bh*31;
  int b = bh >> 2, hh = bh & 3;
  float M = key2f(km[bh]);
  for (int t=tid; t<1024; t+=256){ wkS[t] = wk[hh*1024 + t]; wvS[t] = wv[hh*1024 + t]; }
  __syncthreads();
  int i = tid >> 1, half = tid & 1;       // phase 1: 2 lanes/token
  int w = tid >> 6, l = tid & 63;         // phase 2: wave=row quarter, lane=f pair
  int row0 = w*32;
  bool f1ok = (l < F_-64);
  int fA = l, fB = f1ok ? (l+64) : 0;
  float4 accA[8], accB[8]; float zA = 0.f, zB = 0.f;
  #pragma unroll
  for (int t=0;t<8;++t){ accA[t]=make_float4(0,0,0,0); accB[t]=make_float4(0,0,0,0); }
  for (int it=0; it<8; ++it){
    int p = slice*1024 + it*128 + i;
    { // phase 1: float4 writes
      float h_[32];
      tok_ln_row(x, b, p, pw, pb, ln1g, ln1b, h_);
      float dgp = 0.f;
      float4* kw = (float4*)(kL + i*KVS_ + half*16);
      float4* vw = (float4*)(vL + i*KVS_ + half*16);
      #pragma unroll
      for (int t4=0; t4<4; ++t4){
        float kq[4], vq[4];
        #pragma unroll
        for (int u=0; u<4; ++u){
          int d = half*16 + t4*4 + u;
          kq[u] = bk[hh*32+d] + dotreg(h_, (const float4*)(wkS + d*32));
          dgp += kq[u]*kq[u];
          vq[u] = bv[hh*32+d] + dotreg(h_, (const float4*)(wvS + d*32));
        }
        kw[t4] = make_float4(kq[0],kq[1],kq[2],kq[3]);
        vw[t4] = make_float4(vq[0],vq[1],vq[2],vq[3]);
      }
      dgp += __shfl_xor(dgp, 1, 64);
      if (half==0) dgL[i] = 0.5f*DN2_*dgp;
    }
    __syncthreads();
    { // phase 2: pr loads indexed by (f + zr*it) so they can't be hoisted
      float4 prA[8], prB[8];
      const float4* pga = (const float4*)(proj + (size_t)(fA + zr*it)*32);
      const float4* pgb = (const float4*)(proj + (size_t)(fB + zr*it)*32);
      #pragma unroll
      for (int t=0;t<8;++t){ prA[t]=pga[t]; prB[t]=pgb[t]; }
      for (int ii=row0; ii<row0+32; ++ii){
        const float4* krow = (const float4*)(kL + ii*KVS_);
        float a0=0.f,a1=0.f,a2=0.f,a3=0.f, b0=0.f,b1=0.f,b2=0.f,b3=0.f;
        #pragma unroll
        for (int t=0;t<8;++t){
          float4 kk=krow[t];
          a0 += kk.x*prA[t].x; a1 += kk.y*prA[t].y; a2 += kk.z*prA[t].z; a3 += kk.w*prA[t].w;
          b0 += kk.x*prB[t].x; b1 += kk.y*prB[t].y; b2 += kk.z*prB[t].z; b3 += kk.w*prB[t].w;
        }
        float dg = dgL[ii];
        float kpA = RATIO_*(fexp(((a0+a1)+(a2+a3))*DN_ - dg - M) + 1e-4f);
        float kpB = f1ok ? RATIO_*(fexp(((b0+b1)+(b2+b3))*DN_ - dg - M) + 1e-4f) : 0.f;
        zA += kpA; zB += kpB;
        const float4* vrow = (const float4*)(vL + ii*KVS_);
        #pragma unroll
        for (int t=0;t<8;++t){
          float4 vv = vrow[t];
          fma4(accA[t], kpA, vv);
          fma4(accB[t], kpB, vv);
        }
      }
    }
    __syncthreads();
  }
  // ---- combine 4 wave-partials per f ----
  if (w==1 || w==3){
    int r = (w==1) ? l : (64+l);
    float* rowA = kL + r*KVS_;
    #pragma unroll
    for (int t=0;t<8;++t){
      rowA[4*t+0]=accA[t].x; rowA[4*t+1]=accA[t].y; rowA[4*t+2]=accA[t].z; rowA[4*t+3]=accA[t].w;
    }
    rowA[32] = zA;
    if (f1ok){
      float* rowB = vL + r*KVS_;
      #pragma unroll
      for (int t=0;t<8;++t){
        rowB[4*t+0]=accB[t].x; rowB[4*t+1]=accB[t].y; rowB[4*t+2]=accB[t].z; rowB[4*t+3]=accB[t].w;
      }
      rowB[32] = zB;
    }
  }
  __syncthreads();
  if (w==0 || w==2){
    int r = (w==0) ? l : (64+l);
    const float* rowA = kL + r*KVS_;
    #pragma unroll
    for (int t=0;t<8;++t){
      accA[t].x += rowA[4*t+0]; accA[t].y += rowA[4*t+1];
      accA[t].z += rowA[4*t+2]; accA[t].w += rowA[4*t+3];
    }
    zA += rowA[32];
    if (f1ok){
      const float* rowB = vL + r*KVS_;
      #pragma unroll
      for (int t=0;t<8;++t){
        accB[t].x += rowB[4*t+0]; accB[t].y += rowB[4*t+1];
        accB[t].z += rowB[4*t+2]; accB[t].w += rowB[4*t+3];
      }
      zB += rowB[32];
    }
  }
  __syncthreads();
  if (w==2){
    float* rowA = kL + l*KVS_;
    #pragma unroll
    for (int t=0;t<8;++t){
      rowA[4*t+0]=accA[t].x; rowA[4*t+1]=accA[t].y; rowA[4*t+2]=accA[t].z; rowA[4*t+3]=accA[t].w;
    }
    rowA[32] = zA;
    if (f1ok){
      float* rowB = vL + l*KVS_;
      #pragma unroll
      for (int t=0;t<8;++t){
        rowB[4*t+0]=accB[t].x; rowB[4*t+1]=accB[t].y; rowB[4*t+2]=accB[t].z; rowB[4*t+3]=accB[t].w;
      }
      rowB[32] = zB;
    }
  }
  __syncthreads();
  if (w==0){
    const float* rowA = kL + l*KVS_;
    float* soA = S + (size_t)bh*3520 + (size_t)fA*32;
    #pragma unroll
    for (int t=0;t<8;++t){
      atomicAdd(soA + 4*t+0, accA[t].x + rowA[4*t+0]);
      atomicAdd(soA + 4*t+1, accA[t].y + rowA[4*t+1]);
      atomicAdd(soA + 4*t+2, accA[t].z + rowA[4*t+2]);
      atomicAdd(soA + 4*t+3, accA[t].w + rowA[4*t+3]);
    }
    atomicAdd(z + (size_t)bh*F_ + fA, zA + rowA[32]);
    if (f1ok){
      const float* rowB = vL + l*KVS_;
      float* soB = S + (size_t)bh*3520 + (size_t)(l+64)*32;
      #pragma unroll
      for (int t=0;t<8;++t){
        atomicAdd(soB + 4*t+0, accB[t].x + rowB[4*t+0]);
        atomicAdd(soB + 4*t+1, accB[t].y + rowB[4*t+1]);
        atomicAdd(soB + 4*t+2, accB[t].z + rowB[4*t+2]);
        atomicAdd(soB + 4*t+3, accB[t].w + rowB[4*t+3]);
      }
      atomicAdd(z + (size_t)bh*F_ + l+64, zB + rowB[32]);
    }
  }
}

// ---- 3. per-group sums over last-slice tokens (groups of 128) ----
__global__ void __launch_bounds__(256,2)
k_gsum_last(const float* __restrict__ x, const float* __restrict__ proj,
            const unsigned* __restrict__ km,
            const float* __restrict__ pw, const float* __restrict__ pb,
            const float* __restrict__ ln1g, const float* __restrict__ ln1b,
            const float* __restrict__ wk, const float* __restrict__ bk,
            const float* __restrict__ wv, const float* __restrict__ bv,
            float* __restrict__ gs, float* __restrict__ gz){
  __shared__ float wkS[1024];
  __shared__ float wvS[1024];
  __shared__ float kL[128*KVS_];
  __shared__ float vL[128*KVS_];
  __shared__ float dgL[128];
  int tid = threadIdx.x;
  int bh = blockIdx.x >> 3, g = blockIdx.x & 7;
  int b = bh >> 2, hh = bh & 3;
  float M = key2f(km[bh]);
  for (int t=tid; t<1024; t+=256){ wkS[t] = wk[hh*1024 + t]; wvS[t] = wv[hh*1024 + t]; }
  __syncthreads();
  int i = tid >> 1, half = tid & 1;
  {
    int p = LAST0_ + g*128 + i;
    float h_[32];
    tok_ln_row(x, b, p, pw, pb, ln1g, ln1b, h_);
    float dgp = 0.f;
    float4* kw = (float4*)(kL + i*KVS_ + half*16);
    float4* vw = (float4*)(vL + i*KVS_ + half*16);
    #pragma unroll
    for (int t4=0; t4<4; ++t4){
      float kq[4], vq[4];
      #pragma unroll
      for (int u=0; u<4; ++u){
        int d = half*16 + t4*4 + u;
        kq[u] = bk[hh*32+d] + dotreg(h_, (const float4*)(wkS + d*32));
        dgp += kq[u]*kq[u];
        vq[u] = bv[hh*32+d] + dotreg(h_, (const float4*)(wvS + d*32));
      }
      kw[t4] = make_float4(kq[0],kq[1],kq[2],kq[3]);
      vw[t4] = make_float4(vq[0],vq[1],vq[2],vq[3]);
    }
    dgp += __shfl_xor(dgp, 1, 64);
    if (half==0) dgL[i] = 0.5f*DN2_*dgp;
  }
  __syncthreads();
  if (tid < F_){
    float4 pr[8];
    const float4* pg = (const float4*)(proj + (size_t)tid*32);
    #pragma unroll
    for (int t=0;t<8;++t) pr[t]=pg[t];
    float4 acc[8]; float zacc = 0.f;
    #pragma unroll
    for (int t=0;t<8;++t) acc[t]=make_float4(0,0,0,0);
    #pragma unroll 2
    for (int ii=0; ii<128; ++ii){
      const float4* krow = (const float4*)(kL + ii*KVS_);
      float dd0=0.f, dd1=0.f, dd2=0.f, dd3=0.f;
      #pragma unroll
      for (int t=0;t<8;++t){
        float4 kk=krow[t], pp=pr[t];
        dd0 += kk.x*pp.x; dd1 += kk.y*pp.y;
        dd2 += kk.z*pp.z; dd3 += kk.w*pp.w;
      }
      float dd = (dd0+dd1)+(dd2+dd3);
      float kp = RATIO_*(fexp(dd*DN_ - dgL[ii] - M) + 1e-4f);
      zacc += kp;
      const float4* vrow = (const float4*)(vL + ii*KVS_);
      #pragma unroll
      for (int t=0;t<8;++t) fma4(acc[t], kp, vrow[t]);
    }
    float4* o = (float4*)(gs + (size_t)blockIdx.x*3520 + tid*32);
    #pragma unroll
    for (int t=0;t<8;++t) o[t]=acc[t];
    gz[(size_t)blockIdx.x*F_ + tid] = zacc;
  }
}

// ---- 4. exclusive prefix over the 8 groups, seeded with global S ----
__global__ void k_scan_last(const float* __restrict__ S, const float* __restrict__ z,
                            float* __restrict__ gs, float* __restrict__ gz){
  int bh = blockIdx.x;
  for (int t=threadIdx.x; t<3630; t+=256){
    if (t < 3520){
      float carry = S[(size_t)bh*3520 + t];
      size_t base = (size_t)bh*8*3520 + t;
      for (int g=0; g<8; ++g){
        size_t idx = base + (size_t)g*3520;
        float tv = gs[idx]; gs[idx] = carry; carry += tv;
      }
    } else {
      int f = t - 3520;
      float carry = z[(size_t)bh*F_ + f];
      size_t base = (size_t)bh*8*F_ + f;
      for (int g=0; g<8; ++g){
        size_t idx = base + (size_t)g*F_;
        float tv = gz[idx]; gz[idx] = carry; carry += tv;
      }
    }
  }
}

// ---- 5. tok_last = preproc(last slice) + bo ----
__global__ void k_preproc_last(const float* __restrict__ x, const float* __restrict__ pw,
                               const float* __restrict__ pb, const float* __restrict__ bo,
                               float* __restrict__ tokl){
  int gid = blockIdx.x*256 + threadIdx.x;   // 262144
  int c = gid & 31; int idx = gid >> 5;
  int b = idx >> 10, i = idx & 1023;
  int p = LAST0_ + i;
  const float* xb = x + (size_t)b*3*N_ + p;
  float s = pb[c] + bo[c];
  s += xb[0]           * pw[c*3+0];
  s += xb[(size_t)N_]  * pw[c*3+1];
  s += xb[(size_t)2*N_]* pw[c*3+2];
  tokl[(size_t)gid] = s;
}

// ---- 6. intra attention: feature-split causal loop, bounded-unroll feature gen ----
__global__ void __launch_bounds__(256,1)
k_intra_last(const float* __restrict__ x, const float* __restrict__ proj,
             const unsigned* __restrict__ km,
             const float* __restrict__ pw, const float* __restrict__ pb,
             const float* __restrict__ ln1g, const float* __restrict__ ln1b,
             const float* __restrict__ wq, const float* __restrict__ bq,
             const float* __restrict__ wk, const float* __restrict__ bk,
             const float* __restrict__ wv, const float* __restrict__ bv,
             const float* __restrict__ wo,
             const float* __restrict__ gs, const float* __restrict__ gz,
             float* __restrict__ tokl){
  __shared__ float kpS[64*FS_];   // 28 KB
  __shared__ float vS[64*32];     // 8 KB
  __shared__ float SL[FS_*32];    // 14 KB
  __shared__ float zL[FS_];       // 0.45 KB
  __shared__ float woS[32*32];    // 4 KB : woS[c][d] = wo[c][hh*32+d]
  __shared__ float qT[64*QTS_];   // 7.25 KB : raw q dd staging
  int tid = threadIdx.x;
  int bh = blockIdx.x >> 3, g = blockIdx.x & 7;
  int b = bh >> 2, hh = bh & 3;
  float M = key2f(km[bh]);
  for (int t=tid; t<FS_*32; t+=256) SL[t] = (t < 3520) ? gs[(size_t)blockIdx.x*3520 + t] : 0.f;
  for (int t=tid; t<FS_; t+=256)    zL[t] = (t < F_)   ? gz[(size_t)blockIdx.x*F_ + t] : 0.f;
  for (int t=tid; t<1024; t+=256){ int c = t >> 5, d = t & 31; woS[t] = wo[c*128 + hh*32 + d]; }
  int r = tid >> 2, q = tid & 3;
  int f0 = q*28, e0 = q*8;
  __syncthreads();
  for (int s=0; s<2; ++s){
    int iloc = g*128 + s*64 + r;
    int p = LAST0_ + iloc;
    float q0v[28];
    // ---- feature phase (bounded-unroll global loads) ----
    {
      float h_[32];
      tok_ln_row(x, b, p, pw, pb, ln1g, ln1b, h_);
      { // K features for own f-range -> kpS (LDS dest; rolled loop OK)
        float kr[32]; float kdg = 0.f;
        #pragma unroll
        for (int d=0; d<32; ++d){
          kr[d] = bk[hh*32+d] + dotreg(h_, (const float4*)(wk + (size_t)(hh*32+d)*32));
          kdg += kr[d]*kr[d];
        }
        kdg *= 0.5f*DN2_;
        #pragma unroll 4
        for (int t=0; t<28; ++t){
          int f = f0 + t; float kp = 0.f;
          if (f < F_){
            float dd = dotreg(kr, (const float4*)(proj + (size_t)f*32));
            kp = RATIO_*(fexp(dd*DN_ - kdg - M) + 1e-4f);
          }
          kpS[r*FS_+f] = kp;
        }
      }
      // V for own e-range
      #pragma unroll
      for (int d0=0; d0<8; ++d0){
        int d = e0 + d0;
        vS[r*32+d] = bv[hh*32+d] + dotreg(h_, (const float4*)(wv + (size_t)(hh*32+d)*32));
      }
      { // Q features: rolled dd -> qT (LDS), then unrolled LDS->reg exp
        float qr_[32]; float qdg = 0.f;
        #pragma unroll
        for (int d=0; d<32; ++d){
          qr_[d] = bq[hh*32+d] + dotreg(h_, (const float4*)(wq + (size_t)(hh*32+d)*32));
          qdg += qr_[d]*qr_[d];
        }
        qdg *= 0.5f*DN2_;
        float mxl = -1e30f;
        #pragma unroll 4
        for (int t=0; t<28; ++t){
          int f = f0 + t;
          float dd = (f < F_) ? dotreg(qr_, (const float4*)(proj + (size_t)f*32))*DN_ : -1e30f;
          qT[r*QTS_+t] = dd;
          mxl = fmaxf(mxl, dd);
        }
        mxl = fmaxf(mxl, __shfl_xor(mxl, 1, 64));
        mxl = fmaxf(mxl, __shfl_xor(mxl, 2, 64));
        #pragma unroll
        for (int t=0; t<28; ++t){
          int f = f0 + t;
          q0v[t] = (f < F_) ? RATIO_*(fexp(qT[r*QTS_+t] - qdg - mxl) + 1e-4f) : 0.f;
        }
      }
    }
    __syncthreads();
    // ---- matmul + fused wo (feature-split; shfl score combine) ----
    {
      // S part: partial over own 28 f, all 32 e
      float pacc[32];
      #pragma unroll
      for (int t=0;t<32;++t) pacc[t]=0.f;
      float dens = 0.f, sq = 0.f;
      #pragma unroll
      for (int t=0; t<28; ++t){
        int f = f0 + t; float qv = q0v[t];
        sq += qv;
        dens += qv * zL[f];
        const float4* sr = (const float4*)(SL + f*32);
        #pragma unroll
        for (int e4=0; e4<8; ++e4){
          float4 sv = sr[e4];
          pacc[e4*4+0] += qv*sv.x; pacc[e4*4+1] += qv*sv.y;
          pacc[e4*4+2] += qv*sv.z; pacc[e4*4+3] += qv*sv.w;
        }
      }
      dens += __shfl_xor(dens, 1, 64); dens += __shfl_xor(dens, 2, 64);
      sq   += __shfl_xor(sq,   1, 64); sq   += __shfl_xor(sq,   2, 64);
      // reduce-scatter pacc (xor2 halves then xor1 quarters)
      bool lo2 = ((q & 2) == 0);
      float p16[16];
      #pragma unroll
      for (int t=0;t<16;++t){
        float send = lo2 ? pacc[16+t] : pacc[t];
        float recv = __shfl_xor(send, 2, 64);
        p16[t] = (lo2 ? pacc[t] : pacc[16+t]) + recv;
      }
      bool lo1 = ((q & 1) == 0);
      float4 accA, accB;
      {
        float e8[8];
        #pragma unroll
        for (int t=0;t<8;++t){
          float send = lo1 ? p16[8+t] : p16[t];
          float recv = __shfl_xor(send, 1, 64);
          e8[t] = (lo1 ? p16[t] : p16[8+t]) + recv;
        }
        accA = make_float4(e8[0],e8[1],e8[2],e8[3]);
        accB = make_float4(e8[4],e8[5],e8[6],e8[7]);
      }
      float den = dens;
      // causal j loop: each thread covers its 28 features, shfl-combine score
      for (int j=0; j<=r; ++j){
        const float4* k4 = (const float4*)(kpS + j*FS_ + f0);
        float a0=0.f, a1=0.f, a2=0.f, a3=0.f;
        #pragma unroll
        for (int t4=0; t4<7; ++t4){
          float4 kk = k4[t4];
          a0 += q0v[4*t4+0]*kk.x; a1 += q0v[4*t4+1]*kk.y;
          a2 += q0v[4*t4+2]*kk.z; a3 += q0v[4*t4+3]*kk.w;
        }
        float a = (a0+a1)+(a2+a3);
        a += __shfl_xor(a, 1, 64);
        a += __shfl_xor(a, 2, 64);
        den += a;
        const float4* vv = (const float4*)(vS + j*32 + e0);
        fma4(accA, a, vv[0]); fma4(accB, a, vv[1]);
      }
      den += 1e-6f*sq;
      float dinv = 1.f/den;
      float ao8[8] = { accA.x*dinv, accA.y*dinv, accA.z*dinv, accA.w*dinv,
                       accB.x*dinv, accB.y*dinv, accB.z*dinv, accB.w*dinv };
      // wo epilogue: rolling per-c shfl-reduce; keep only own 8 outputs
      float own[8];
      #pragma unroll
      for (int c=0; c<32; ++c){
        float s2 = 0.f;
        #pragma unroll
        for (int t=0; t<8; ++t) s2 += ao8[t]*woS[c*32 + e0 + t];
        s2 += __shfl_xor(s2, 1, 64);
        s2 += __shfl_xor(s2, 2, 64);
        if ((c >> 3) == q) own[c & 7] = s2;
      }
      float* dst = tokl + ((size_t)b*1024 + iloc)*32;
      #pragma unroll
      for (int t=0; t<8; ++t) atomicAdd(dst + q*8 + t, own[t]);
    }
    __syncthreads();
    // ---- carry update between sub-chunks ----
    if (s == 0){
      for (int t=tid; t<3520; t+=256){
        int f = t >> 5, e = t & 31;
        float ssum0 = 0.f, ssum1 = 0.f;
        for (int jj=0; jj<64; jj+=2){
          ssum0 += kpS[jj*FS_+f]*vS[jj*32+e];
          ssum1 += kpS[(jj+1)*FS_+f]*vS[(jj+1)*32+e];
        }
        SL[t] += ssum0 + ssum1;
      }
      for (int t=tid; t<F_; t+=256){
        float ssum0 = 0.f, ssum1 = 0.f;
        for (int jj=0; jj<64; jj+=2){
          ssum0 += kpS[jj*FS_+t];
          ssum1 += kpS[(jj+1)*FS_+t];
        }
        zL[t] += ssum0 + ssum1;
      }
      __syncthreads();
    }
  }
}

// ---- 7. fused LN2 + FF + residual on last slice ----
__global__ void __launch_bounds__(256,1)
k_ff_last(float* __restrict__ tok,
          const float* __restrict__ ln2g, const float* __restrict__ ln2b,
          const float* __restrict__ w1, const float* __restrict__ b1,
          const float* __restrict__ w2, const float* __restrict__ b2){
  __shared__ float w1s[128*32];
  __shared__ float w2t[128*32];
  __shared__ float b1s[128];
  __shared__ float b2s[32];
  __shared__ float lg[32], lb[32];
  int tid = threadIdx.x;
  for (int t=tid; t<4096; t+=256){
    w1s[t] = w1[t];
    int j = t >> 5, c = t & 31;
    w2t[t] = w2[c*128 + j];
  }
  if (tid < 128) b1s[tid] = b1[tid];
  if (tid < 32){ b2s[tid] = b2[tid]; lg[tid] = ln2g[tid]; lb[tid] = ln2b[tid]; }
  __syncthreads();
  size_t bp = (size_t)blockIdx.x*256 + tid;
  float* rowp = tok + bp*32;
  float r_[32], h_[32];
  { const float4* tr = (const float4*)rowp;
    float mean = 0.f;
    #pragma unroll
    for (int t=0;t<8;++t){
      float4 v = tr[t];
      r_[4*t+0]=v.x; r_[4*t+1]=v.y; r_[4*t+2]=v.z; r_[4*t+3]=v.w;
      mean += v.x+v.y+v.z+v.w;
    }
    mean *= (1.f/32.f);
    float var = 0.f;
    #pragma unroll
    for (int t=0;t<32;++t){ float d=r_[t]-mean; var += d*d; }
    var *= (1.f/32.f);
    float rs = rsqrtf(var + 1e-5f);
    #pragma unroll
    for (int t=0;t<32;++t) h_[t] = (r_[t]-mean)*rs*lg[t] + lb[t];
  }
  float4 o[8];
  { const float4* bb = (const float4*)b2s;
    #pragma unroll
    for (int t=0;t<8;++t) o[t]=bb[t]; }
  for (int j=0; j<128; ++j){
    float a = b1s[j] + dotreg(h_, (const float4*)(w1s + j*32));
    float gl = 0.5f*a*(1.f + erff(a*0.70710678118654752f));
    const float4* wr = (const float4*)(w2t + j*32);
    #pragma unroll
    for (int t=0;t<8;++t) fma4(o[t], gl, wr[t]);
  }
  #pragma unroll
  for (int t=0;t<8;++t){
    float4 wv2;
    wv2.x = r_[4*t+0] + o[t].x;
    wv2.y = r_[4*t+1] + o[t].y;
    wv2.z = r_[4*t+2] + o[t].z;
    wv2.w = r_[4*t+3] + o[t].w;
    ((float4*)rowp)[t] = wv2;
  }
}

// ---- 8. readout ----
__global__ void k_readout(const float* __restrict__ tokl, const float* __restrict__ xin,
                          const float* __restrict__ tcw, const float* __restrict__ tcb,
                          const float* __restrict__ row, const float* __restrict__ rob,
                          float* __restrict__ out){
  __shared__ float red[256];
  int b = blockIdx.x; int tid = threadIdx.x;
  float acc = 0.f;
  for (int it=0; it<4; ++it){
    int px = it*256 + tid;
    int y = px >> 5, xx = px & 31;
    float s = 0.f;
    for (int ic=0; ic<33; ++ic){
      for (int ky=0; ky<5; ++ky){
        int yy = y + ky - 2; if (yy < 0 || yy >= 32) continue;
        for (int kx=0; kx<5; ++kx){
          int xc = xx + kx - 2; if (xc < 0 || xc >= 32) continue;
          float v;
          if (ic < 32) v = tokl[((size_t)b*1024 + yy*32 + xc)*32 + ic];
          else         v = xin[((size_t)b*3 + 2)*N_ + yy*32 + xc];
          s += v * tcw[(ic*5+ky)*5+kx];
        }
      }
    }
    acc += s;
  }
  red[tid] = acc; __syncthreads();
  for (int st=128; st>0; st>>=1){
    if (tid < st) red[tid] += red[tid+st];
    __syncthreads();
  }
  if (tid==0) out[b] = (red[0]*(1.f/1024.f) + tcb[0]) * row[0] + rob[0];
}

extern "C" void kernel_launch(void* const* d_in, const int* in_sizes, int n_in,
                              void* d_out, int out_size, void* d_ws, size_t ws_size,
                              hipStream_t stream){
  const float* x    = (const float*)d_in[0];
  const float* pw   = (const float*)d_in[1];
  const float* pb   = (const float*)d_in[2];
  const float* ln1g = (const float*)d_in[3];
  const float* ln1b = (const float*)d_in[4];
  const float* wq   = (const float*)d_in[5];
  const float* bq   = (const float*)d_in[6];
  const float* wk   = (const float*)d_in[7];
  const float* bk   = (const float*)d_in[8];
  const float* wv   = (const float*)d_in[9];
  const float* bv   = (const float*)d_in[10];
  const float* proj = (const float*)d_in[11];
  const float* wo   = (const float*)d_in[12];
  const float* bo   = (const float*)d_in[13];
  const float* ln2g = (const float*)d_in[14];
  const float* ln2b = (const float*)d_in[15];
  const float* ffw1 = (const float*)d_in[16];
  const float* ffb1 = (const float*)d_in[17];
  const float* ffw2 = (const float*)d_in[18];
  const float* ffb2 = (const float*)d_in[19];
  const float* tcw  = (const float*)d_in[20];
  const float* tcb  = (const float*)d_in[21];
  const float* row_ = (const float*)d_in[22];
  const float* rob  = (const float*)d_in[23];

  float* ws   = (float*)d_ws;
  float* tokl = ws + OFF_TOKL;
  float* S    = ws + OFF_S;
  float* z    = ws + OFF_Z;
  float* gs   = ws + OFF_GS;
  float* gz   = ws + OFF_GZ;
  unsigned* km = (unsigned*)(ws + OFF_KM);

  if (ws_size < WS_NEED){
    k_out_zero<<<1, 64, 0, stream>>>((float*)d_out);
    return;
  }
  int zr = (int)(ws_size >> 62);   // runtime 0, opaque to the compiler

  k_zero<<<(112640+3520+255)/256, 256, 0, stream>>>(S, 112640+3520);  // S and z contiguous
  k_kmax_init<<<1, 64, 0, stream>>>(km);
  k_kmax<<<BH_*32, 256, 0, stream>>>(x, proj, pw, pb, ln1g, ln1b, wk, bk, km);
  k_state<<<BH_*31, 256, 0, stream>>>(x, proj, km, pw, pb, ln1g, ln1b, wk, bk, wv, bv, S, z, zr);
  k_gsum_last<<<BH_*8, 256, 0, stream>>>(x, proj, km, pw, pb, ln1g, ln1b, wk, bk, wv, bv, gs, gz);
  k_scan_last<<<BH_, 256, 0, stream>>>(S, z, gs, gz);
  k_preproc_last<<<1024, 256, 0, stream>>>(x, pw, pb, bo, tokl);
  k_intra_last<<<BH_*8, 256, 0, stream>>>(x, proj, km, pw, pb, ln1g, ln1b,
                                          wq, bq, wk, bk, wv, bv, wo, gs, gz, tokl);
  k_ff_last<<<32, 256, 0, stream>>>(tokl, ln2g, ln2b, ffw1, ffb1, ffw2, ffb2);
  k_readout<<<B_, 256, 0, stream>>>(tokl, x, tcw, tcb, row_, rob, (float*)d_out);
}